// Round 5
// baseline (320.902 us; speedup 1.0000x reference)
//
#include <hip/hip_runtime.h>
#include <math.h>

#define N_SEQ 384
#define DIM 512
#define BATCH 8
#define M_ROWS (BATCH * N_SEQ)   // 3072
#define QK_COLS (2 * DIM)        // 1024: cols 0..511 = q, 512..1023 = k

typedef short v8s __attribute__((ext_vector_type(8)));   // 8 bf16 (4 VGPRs)
typedef float v4f __attribute__((ext_vector_type(4)));   // MFMA f32 acc

__device__ inline unsigned short f2bf(float f) {
    union { float f; unsigned u; } c; c.f = f;
    unsigned u = c.u;
    u += 0x7fffu + ((u >> 16) & 1u);   // RNE (inputs finite)
    return (unsigned short)(u >> 16);
}

// ---------------------------------------------------------------------------
// Kernel 1: fused cast + lr-GEMV + MFMA qk projection.
// qk_bf[3072x1024] = bf16(h) @ [bf16(Wq); bf16(Wk)]^T (+bq on q half).
// Loads fp32 operands straight from HBM/L2, converts to bf16 while staging
// into LDS (no bf16 intermediate in HBM).  64x64 tile, grid (48 rows,16 cols)
// = 768 blocks (3/CU).  x varies fastest -> the 48 blockIdx.y==0 blocks are
// dispatched first; they additionally compute left/right for their 64 rows.
// LDS rows padded to 40 bf16: bank stride 20 -> 2-way aliasing (free, m136).
// ---------------------------------------------------------------------------
__global__ __launch_bounds__(256) void qk_gemm_fused(
    const float* __restrict__ h, const float* __restrict__ Wq,
    const float* __restrict__ Wk, const float* __restrict__ bq,
    const float* __restrict__ wlr, const float* __restrict__ blr,
    const float* __restrict__ wrl, const float* __restrict__ brl,
    unsigned short* __restrict__ C, float* __restrict__ left,
    float* __restrict__ right)
{
    __shared__ unsigned short As[64][40];
    __shared__ unsigned short Bs[64][40];
    const int bm = blockIdx.x * 64;          // row block 0..47
    const int bn = blockIdx.y * 64;          // col block 0..15 (of QK_COLS)
    const float* __restrict__ Wbase =
        (bn < DIM) ? (Wq + (size_t)bn * DIM) : (Wk + (size_t)(bn - DIM) * DIM);
    const int t = threadIdx.x;
    const int wv = t >> 6, lane = t & 63;
    const int wm = (wv & 1) * 32, wn = (wv >> 1) * 32;
    const int lm = lane & 15, quad = lane >> 4;
    const int srow = t >> 2, skc = (t & 3) * 8;

    // ---- lr GEMVs (only the 48 first-dispatched blocks; wave wv: 16 rows)
    if (blockIdx.y == 0) {
        float wl[8], wr[8];
#pragma unroll
        for (int u = 0; u < 8; ++u) {
            wl[u] = wlr[u * 64 + lane];
            wr[u] = wrl[u * 64 + lane];
        }
        for (int rr = 0; rr < 16; ++rr) {
            const int r = wv * 16 + rr;
            const float* hr = h + (size_t)(bm + r) * DIM;
            float sl = 0.f, sr = 0.f;
#pragma unroll
            for (int u = 0; u < 8; ++u) {
                const float hv = hr[u * 64 + lane];
                sl = fmaf(hv, wl[u], sl);
                sr = fmaf(hv, wr[u], sr);
            }
#pragma unroll
            for (int off = 32; off > 0; off >>= 1) {
                sl += __shfl_down(sl, off);
                sr += __shfl_down(sr, off);
            }
            if (lane == 0) {
                left[bm + r]  = sl + blr[0];
                right[bm + r] = sr + brl[0];
            }
        }
    }

    // ---- MFMA main loop, BK=32, fp32 load -> bf16 LDS staging
    v4f acc[2][2] = {};
    for (int k0 = 0; k0 < DIM; k0 += 32) {
        const float* ap = h + (size_t)(bm + srow) * DIM + k0 + skc;
        const float* bp = Wbase + (size_t)srow * DIM + k0 + skc;
        const float4 a0 = *(const float4*)ap;
        const float4 a1 = *(const float4*)(ap + 4);
        const float4 b0 = *(const float4*)bp;
        const float4 b1 = *(const float4*)(bp + 4);
        ushort4 oa0, oa1, ob0, ob1;
        oa0.x = f2bf(a0.x); oa0.y = f2bf(a0.y); oa0.z = f2bf(a0.z); oa0.w = f2bf(a0.w);
        oa1.x = f2bf(a1.x); oa1.y = f2bf(a1.y); oa1.z = f2bf(a1.z); oa1.w = f2bf(a1.w);
        ob0.x = f2bf(b0.x); ob0.y = f2bf(b0.y); ob0.z = f2bf(b0.z); ob0.w = f2bf(b0.w);
        ob1.x = f2bf(b1.x); ob1.y = f2bf(b1.y); ob1.z = f2bf(b1.z); ob1.w = f2bf(b1.w);
        __syncthreads();
        *(ushort4*)&As[srow][skc]     = oa0;
        *(ushort4*)&As[srow][skc + 4] = oa1;
        *(ushort4*)&Bs[srow][skc]     = ob0;
        *(ushort4*)&Bs[srow][skc + 4] = ob1;
        __syncthreads();
        v8s af[2], bf[2];
#pragma unroll
        for (int i = 0; i < 2; ++i) af[i] = *(const v8s*)&As[wm + i * 16 + lm][quad * 8];
#pragma unroll
        for (int j = 0; j < 2; ++j) bf[j] = *(const v8s*)&Bs[wn + j * 16 + lm][quad * 8];
#pragma unroll
        for (int i = 0; i < 2; ++i)
#pragma unroll
            for (int j = 0; j < 2; ++j)
                acc[i][j] = __builtin_amdgcn_mfma_f32_16x16x32_bf16(af[i], bf[j], acc[i][j], 0, 0, 0);
    }
#pragma unroll
    for (int i = 0; i < 2; ++i)
#pragma unroll
        for (int j = 0; j < 2; ++j) {
            const int col = bn + wn + j * 16 + lm;
            const float bias = (col < DIM) ? bq[col] : 0.f;
#pragma unroll
            for (int r = 0; r < 4; ++r) {
                const int row = bm + wm + i * 16 + quad * 4 + r;
                C[(size_t)row * QK_COLS + col] = f2bf(acc[i][j][r] + bias);
            }
        }
}

// ---------------------------------------------------------------------------
// Kernel 2: MFMA batched scores q_b @ k_b^T fused with
// raw = clip(alpha*s + beta*d + gamma).  64x64 tile, grid 6x6x8 = 288 blocks.
// ---------------------------------------------------------------------------
__global__ __launch_bounds__(256) void score_gemm(
    const unsigned short* __restrict__ QK, const float* __restrict__ left,
    const float* __restrict__ right, const float* __restrict__ alpha,
    const float* __restrict__ beta, const float* __restrict__ gamma,
    float* __restrict__ raw)
{
    __shared__ unsigned short As[64][40];
    __shared__ unsigned short Bs[64][40];
    const int b  = blockIdx.z;
    const int bi = blockIdx.x * 64, bj = blockIdx.y * 64;
    const int t = threadIdx.x;
    const int wv = t >> 6, lane = t & 63;
    const int wm = (wv & 1) * 32, wn = (wv >> 1) * 32;
    const int lm = lane & 15, quad = lane >> 4;
    const int srow = t >> 2, skc = (t & 3) * 8;
    const unsigned short* qb = QK + (size_t)(b * N_SEQ) * QK_COLS;
    v4f acc[2][2] = {};
    for (int k0 = 0; k0 < DIM; k0 += 32) {
        v8s a0 = *(const v8s*)(qb + (size_t)(bi + srow) * QK_COLS + k0 + skc);
        v8s b0 = *(const v8s*)(qb + (size_t)(bj + srow) * QK_COLS + DIM + k0 + skc);
        __syncthreads();
        *(v8s*)&As[srow][skc] = a0;
        *(v8s*)&Bs[srow][skc] = b0;
        __syncthreads();
        v8s af[2], bf[2];
#pragma unroll
        for (int i = 0; i < 2; ++i) af[i] = *(const v8s*)&As[wm + i * 16 + lm][quad * 8];
#pragma unroll
        for (int j = 0; j < 2; ++j) bf[j] = *(const v8s*)&Bs[wn + j * 16 + lm][quad * 8];
#pragma unroll
        for (int i = 0; i < 2; ++i)
#pragma unroll
            for (int j = 0; j < 2; ++j)
                acc[i][j] = __builtin_amdgcn_mfma_f32_16x16x32_bf16(af[i], bf[j], acc[i][j], 0, 0, 0);
    }
    const float al = alpha[0], be = beta[0], ga = gamma[0];
#pragma unroll
    for (int i = 0; i < 2; ++i)
#pragma unroll
        for (int j = 0; j < 2; ++j) {
            const int jcol = bj + wn + j * 16 + lm;
#pragma unroll
            for (int r = 0; r < 4; ++r) {
                const int irow = bi + wm + i * 16 + quad * 4 + r;
                const float lv = left[b * N_SEQ + irow];
                const float rv = right[b * N_SEQ + irow];
                const float dterm = (jcol >= irow) ? lv : rv;
                float v = fmaf(al, acc[i][j][r], fmaf(be, dterm, ga));
                v = fminf(fmaxf(v, -16.f), 14.f);
                raw[((size_t)b * N_SEQ + irow) * N_SEQ + jcol] = v;
            }
        }
}

// ---------------------------------------------------------------------------
// Kernel 3: per (b,i) row finalize.  l1 = log(1-sigmoid(x)), lp = x + l1,
// prefix-scan of l1, then the two analytic mask intervals:
//   i<j: (P[j]-P[i+1]) + (P[i]-P[max(2i-j+1,0)])
//   i>j: (P[i]-P[j+1]) + (P[min(2i-j+1,N)]-P[i+1])
// Grid 384x8 = 3072 blocks.  masking_matrix input never touched.
// ---------------------------------------------------------------------------
__global__ __launch_bounds__(384) void finalize(
    const float* __restrict__ raw, const float* __restrict__ mask,
    float* __restrict__ out_r, float* __restrict__ out_am)
{
    const int n = N_SEQ;
    const int i = blockIdx.x;
    const int b = blockIdx.y;
    const int j = threadIdx.x;     // 0..383
    __shared__ float P[N_SEQ + 1];
    __shared__ float wsum[6];
    const float x  = raw[((size_t)b * n + i) * n + j];
    const float l1 = -log1pf(expf(x));    // log(1 - sigmoid(x))
    const float lp = x + l1;              // log sigmoid(x)
    const int lane = j & 63, w = j >> 6;
    float v = l1;
#pragma unroll
    for (int off = 1; off < 64; off <<= 1) {
        const float tt = __shfl_up(v, off);
        if (lane >= off) v += tt;
    }
    if (lane == 63) wsum[w] = v;
    __syncthreads();
    float woff = 0.f;
    for (int t = 0; t < w; ++t) woff += wsum[t];
    P[j + 1] = v + woff;
    if (j == 0) P[0] = 0.f;
    __syncthreads();
    float s = 0.f;
    if (i < j) {
        int lo2 = 2 * i - j + 1; if (lo2 < 0) lo2 = 0;
        s = (P[j] - P[i + 1]) + (P[i] - P[lo2]);
    } else if (i > j) {
        int hi2 = 2 * i - j + 1; if (hi2 > n) hi2 = n;
        s = (P[i] - P[j + 1]) + (P[hi2] - P[i + 1]);
    }
    float r = s + lp;
    if (i == j) r -= 10000.f;
    const size_t o = ((size_t)b * n + i) * n + j;
    out_r[o]  = r;
    out_am[o] = mask[b * n + i] * mask[b * n + j];
}

// ---------------------------------------------------------------------------
extern "C" void kernel_launch(void* const* d_in, const int* in_sizes, int n_in,
                              void* d_out, int out_size, void* d_ws, size_t ws_size,
                              hipStream_t stream) {
    const float* h     = (const float*)d_in[0];
    const float* mask  = (const float*)d_in[1];
    const float* Wq    = (const float*)d_in[2];
    const float* bq    = (const float*)d_in[3];
    const float* Wk    = (const float*)d_in[4];
    const float* wlr   = (const float*)d_in[5];
    const float* blr   = (const float*)d_in[6];
    const float* wrl   = (const float*)d_in[7];
    const float* brl   = (const float*)d_in[8];
    const float* alpha = (const float*)d_in[9];
    const float* beta  = (const float*)d_in[10];
    const float* gamma = (const float*)d_in[11];
    // d_in[12] (masking_matrix) intentionally unused: analytic k-intervals +
    // prefix sum replace the O(N^3) einsum.

    unsigned short* qk_bf = (unsigned short*)d_ws;                 // 3072x1024
    float* left  = (float*)(qk_bf + (size_t)M_ROWS * QK_COLS);     // 3072
    float* right = left + M_ROWS;                                  // 3072
    float* raw   = right + M_ROWS;                                 // 8*384*384

    float* out_r  = (float*)d_out;
    float* out_am = out_r + (size_t)BATCH * N_SEQ * N_SEQ;

    dim3 g1(M_ROWS / 64, QK_COLS / 64);         // 48 x 16
    qk_gemm_fused<<<g1, 256, 0, stream>>>(h, Wq, Wk, bq, wlr, blr, wrl, brl,
                                          qk_bf, left, right);
    dim3 g2(N_SEQ / 64, N_SEQ / 64, BATCH);     // 6 x 6 x 8
    score_gemm<<<g2, 256, 0, stream>>>(qk_bf, left, right, alpha, beta, gamma, raw);
    dim3 g3(N_SEQ, BATCH);
    finalize<<<g3, 384, 0, stream>>>(raw, mask, out_r, out_am);
}

// Round 6
// 301.910 us; speedup vs baseline: 1.0629x; 1.0629x over previous
//
#include <hip/hip_runtime.h>
#include <math.h>

#define N_SEQ 384
#define DIM 512
#define BATCH 8
#define M_ROWS (BATCH * N_SEQ)   // 3072
#define QK_COLS (2 * DIM)        // 1024: cols 0..511 = q, 512..1023 = k

typedef short v8s __attribute__((ext_vector_type(8)));   // 8 bf16 (4 VGPRs)
typedef float v4f __attribute__((ext_vector_type(4)));   // MFMA f32 acc

__device__ inline unsigned short f2bf(float f) {
    union { float f; unsigned u; } c; c.f = f;
    unsigned u = c.u;
    u += 0x7fffu + ((u >> 16) & 1u);   // RNE (inputs finite)
    return (unsigned short)(u >> 16);
}

// ---------------------------------------------------------------------------
// Kernel 0: prep = cast h/Wq/Wk -> bf16  +  left/right GEMVs, fused.
// One wave per 512-elem row.  Wave-tasks 0..3071 = h rows (cast + GEMV),
// 3072..4095 = Wq/Wk rows (cast only).  Grid 1024 x 256.
// Cast ONCE here, reuse bf16 in the GEMMs (round-5 cast-in-loop regressed).
// ---------------------------------------------------------------------------
__global__ __launch_bounds__(256) void prep(
    const float* __restrict__ h, const float* __restrict__ Wq,
    const float* __restrict__ Wk, const float* __restrict__ wlr,
    const float* __restrict__ blr, const float* __restrict__ wrl,
    const float* __restrict__ brl, unsigned short* __restrict__ h_bf,
    unsigned short* __restrict__ w_bf, float* __restrict__ left,
    float* __restrict__ right)
{
    const int wv = threadIdx.x >> 6, lane = threadIdx.x & 63;
    const int task = blockIdx.x * 4 + wv;          // 0..4095
    const float* src; unsigned short* dst;
    if (task < M_ROWS) {
        src = h + (size_t)task * DIM;
        dst = h_bf + (size_t)task * DIM;
    } else {
        const int r = task - M_ROWS;               // 0..1023
        src = (r < DIM) ? (Wq + (size_t)r * DIM) : (Wk + (size_t)(r - DIM) * DIM);
        dst = w_bf + (size_t)r * DIM;
    }
    const float4* s4 = (const float4*)src;
    const float4 v0 = s4[lane];        // elems lane*4 .. +3
    const float4 v1 = s4[lane + 64];   // elems 256+lane*4 .. +3
    ushort4 o0, o1;
    o0.x = f2bf(v0.x); o0.y = f2bf(v0.y); o0.z = f2bf(v0.z); o0.w = f2bf(v0.w);
    o1.x = f2bf(v1.x); o1.y = f2bf(v1.y); o1.z = f2bf(v1.z); o1.w = f2bf(v1.w);
    *(ushort4*)(dst + lane * 4)       = o0;
    *(ushort4*)(dst + 256 + lane * 4) = o1;
    if (task < M_ROWS) {
        const float4* wl4 = (const float4*)wlr;
        const float4* wr4 = (const float4*)wrl;
        const float4 a0 = wl4[lane], a1 = wl4[lane + 64];
        const float4 c0 = wr4[lane], c1 = wr4[lane + 64];
        float sl = v0.x * a0.x + v0.y * a0.y + v0.z * a0.z + v0.w * a0.w
                 + v1.x * a1.x + v1.y * a1.y + v1.z * a1.z + v1.w * a1.w;
        float sr = v0.x * c0.x + v0.y * c0.y + v0.z * c0.z + v0.w * c0.w
                 + v1.x * c1.x + v1.y * c1.y + v1.z * c1.z + v1.w * c1.w;
#pragma unroll
        for (int off = 32; off > 0; off >>= 1) {
            sl += __shfl_down(sl, off);
            sr += __shfl_down(sr, off);
        }
        if (lane == 0) {
            left[task]  = sl + blr[0];
            right[task] = sr + brl[0];
        }
    }
}

// ---------------------------------------------------------------------------
// Kernel 1: MFMA qk projection, 64x64 tile, BK=64 (two 32-wide LDS stages per
// barrier-pair -> 8 MFMAs/wave between barriers, 8 K-iters).
// Grid 48x16 = 768 blocks (3/CU).  LDS rows padded to 40 bf16 (2-way = free).
// ---------------------------------------------------------------------------
__global__ __launch_bounds__(256) void qk_gemm(
    const unsigned short* __restrict__ A,   // h_bf 3072x512
    const unsigned short* __restrict__ Bm,  // w_bf 1024x512
    const float* __restrict__ bq,
    unsigned short* __restrict__ C)         // qk_bf 3072x1024
{
    __shared__ unsigned short As[2][64][40];
    __shared__ unsigned short Bs[2][64][40];
    const int bm = blockIdx.x * 64;
    const int bn = blockIdx.y * 64;
    const int t = threadIdx.x;
    const int wv = t >> 6, lane = t & 63;
    const int wm = (wv & 1) * 32, wn = (wv >> 1) * 32;
    const int lm = lane & 15, quad = lane >> 4;
    const int srow = t >> 2, skc = (t & 3) * 8;
    v4f acc[2][2] = {};
    for (int k0 = 0; k0 < DIM; k0 += 64) {
        const unsigned short* ap = A  + (size_t)(bm + srow) * DIM + k0 + skc;
        const unsigned short* bp = Bm + (size_t)(bn + srow) * DIM + k0 + skc;
        v8s a0 = *(const v8s*)ap;
        v8s a1 = *(const v8s*)(ap + 32);
        v8s b0 = *(const v8s*)bp;
        v8s b1 = *(const v8s*)(bp + 32);
        __syncthreads();
        *(v8s*)&As[0][srow][skc] = a0;
        *(v8s*)&As[1][srow][skc] = a1;
        *(v8s*)&Bs[0][srow][skc] = b0;
        *(v8s*)&Bs[1][srow][skc] = b1;
        __syncthreads();
#pragma unroll
        for (int half = 0; half < 2; ++half) {
            v8s af[2], bf[2];
#pragma unroll
            for (int i = 0; i < 2; ++i) af[i] = *(const v8s*)&As[half][wm + i * 16 + lm][quad * 8];
#pragma unroll
            for (int j = 0; j < 2; ++j) bf[j] = *(const v8s*)&Bs[half][wn + j * 16 + lm][quad * 8];
#pragma unroll
            for (int i = 0; i < 2; ++i)
#pragma unroll
                for (int j = 0; j < 2; ++j)
                    acc[i][j] = __builtin_amdgcn_mfma_f32_16x16x32_bf16(af[i], bf[j], acc[i][j], 0, 0, 0);
        }
    }
#pragma unroll
    for (int i = 0; i < 2; ++i)
#pragma unroll
        for (int j = 0; j < 2; ++j) {
            const int col = bn + wn + j * 16 + lm;
            const float bias = (col < DIM) ? bq[col] : 0.f;
#pragma unroll
            for (int r = 0; r < 4; ++r) {
                const int row = bm + wm + i * 16 + quad * 4 + r;
                C[(size_t)row * QK_COLS + col] = f2bf(acc[i][j][r] + bias);
            }
        }
}

// ---------------------------------------------------------------------------
// Kernel 2: MFMA batched scores q_b @ k_b^T fused with
// raw = clip(alpha*s + beta*d + gamma).  64x64 tile, BK=64, grid 6x6x8 = 288.
// ---------------------------------------------------------------------------
__global__ __launch_bounds__(256) void score_gemm(
    const unsigned short* __restrict__ QK, const float* __restrict__ left,
    const float* __restrict__ right, const float* __restrict__ alpha,
    const float* __restrict__ beta, const float* __restrict__ gamma,
    float* __restrict__ raw)
{
    __shared__ unsigned short As[2][64][40];
    __shared__ unsigned short Bs[2][64][40];
    const int b  = blockIdx.z;
    const int bi = blockIdx.x * 64, bj = blockIdx.y * 64;
    const int t = threadIdx.x;
    const int wv = t >> 6, lane = t & 63;
    const int wm = (wv & 1) * 32, wn = (wv >> 1) * 32;
    const int lm = lane & 15, quad = lane >> 4;
    const int srow = t >> 2, skc = (t & 3) * 8;
    const unsigned short* qb = QK + (size_t)(b * N_SEQ) * QK_COLS;
    v4f acc[2][2] = {};
    for (int k0 = 0; k0 < DIM; k0 += 64) {
        const unsigned short* ap = qb + (size_t)(bi + srow) * QK_COLS + k0 + skc;
        const unsigned short* bp = qb + (size_t)(bj + srow) * QK_COLS + DIM + k0 + skc;
        v8s a0 = *(const v8s*)ap;
        v8s a1 = *(const v8s*)(ap + 32);
        v8s b0 = *(const v8s*)bp;
        v8s b1 = *(const v8s*)(bp + 32);
        __syncthreads();
        *(v8s*)&As[0][srow][skc] = a0;
        *(v8s*)&As[1][srow][skc] = a1;
        *(v8s*)&Bs[0][srow][skc] = b0;
        *(v8s*)&Bs[1][srow][skc] = b1;
        __syncthreads();
#pragma unroll
        for (int half = 0; half < 2; ++half) {
            v8s af[2], bf[2];
#pragma unroll
            for (int i = 0; i < 2; ++i) af[i] = *(const v8s*)&As[half][wm + i * 16 + lm][quad * 8];
#pragma unroll
            for (int j = 0; j < 2; ++j) bf[j] = *(const v8s*)&Bs[half][wn + j * 16 + lm][quad * 8];
#pragma unroll
            for (int i = 0; i < 2; ++i)
#pragma unroll
                for (int j = 0; j < 2; ++j)
                    acc[i][j] = __builtin_amdgcn_mfma_f32_16x16x32_bf16(af[i], bf[j], acc[i][j], 0, 0, 0);
        }
    }
    const float al = alpha[0], be = beta[0], ga = gamma[0];
#pragma unroll
    for (int i = 0; i < 2; ++i)
#pragma unroll
        for (int j = 0; j < 2; ++j) {
            const int jcol = bj + wn + j * 16 + lm;
#pragma unroll
            for (int r = 0; r < 4; ++r) {
                const int irow = bi + wm + i * 16 + quad * 4 + r;
                const float lv = left[b * N_SEQ + irow];
                const float rv = right[b * N_SEQ + irow];
                const float dterm = (jcol >= irow) ? lv : rv;
                float v = fmaf(al, acc[i][j][r], fmaf(be, dterm, ga));
                v = fminf(fmaxf(v, -16.f), 14.f);
                raw[((size_t)b * N_SEQ + irow) * N_SEQ + jcol] = v;
            }
        }
}

// ---------------------------------------------------------------------------
// Kernel 3: per (b,i) row finalize.  l1 = log(1-sigmoid(x)), lp = x + l1,
// prefix-scan of l1, then the two analytic mask intervals:
//   i<j: (P[j]-P[i+1]) + (P[i]-P[max(2i-j+1,0)])
//   i>j: (P[i]-P[j+1]) + (P[min(2i-j+1,N)]-P[i+1])
// Grid 384x8 = 3072 blocks.  masking_matrix input never touched.
// ---------------------------------------------------------------------------
__global__ __launch_bounds__(384) void finalize(
    const float* __restrict__ raw, const float* __restrict__ mask,
    float* __restrict__ out_r, float* __restrict__ out_am)
{
    const int n = N_SEQ;
    const int i = blockIdx.x;
    const int b = blockIdx.y;
    const int j = threadIdx.x;     // 0..383
    __shared__ float P[N_SEQ + 1];
    __shared__ float wsum[6];
    const float x  = raw[((size_t)b * n + i) * n + j];
    const float l1 = -log1pf(expf(x));    // log(1 - sigmoid(x))
    const float lp = x + l1;              // log sigmoid(x)
    const int lane = j & 63, w = j >> 6;
    float v = l1;
#pragma unroll
    for (int off = 1; off < 64; off <<= 1) {
        const float tt = __shfl_up(v, off);
        if (lane >= off) v += tt;
    }
    if (lane == 63) wsum[w] = v;
    __syncthreads();
    float woff = 0.f;
    for (int t = 0; t < w; ++t) woff += wsum[t];
    P[j + 1] = v + woff;
    if (j == 0) P[0] = 0.f;
    __syncthreads();
    float s = 0.f;
    if (i < j) {
        int lo2 = 2 * i - j + 1; if (lo2 < 0) lo2 = 0;
        s = (P[j] - P[i + 1]) + (P[i] - P[lo2]);
    } else if (i > j) {
        int hi2 = 2 * i - j + 1; if (hi2 > n) hi2 = n;
        s = (P[i] - P[j + 1]) + (P[hi2] - P[i + 1]);
    }
    float r = s + lp;
    if (i == j) r -= 10000.f;
    const size_t o = ((size_t)b * n + i) * n + j;
    out_r[o]  = r;
    out_am[o] = mask[b * n + i] * mask[b * n + j];
}

// ---------------------------------------------------------------------------
extern "C" void kernel_launch(void* const* d_in, const int* in_sizes, int n_in,
                              void* d_out, int out_size, void* d_ws, size_t ws_size,
                              hipStream_t stream) {
    const float* h     = (const float*)d_in[0];
    const float* mask  = (const float*)d_in[1];
    const float* Wq    = (const float*)d_in[2];
    const float* bq    = (const float*)d_in[3];
    const float* Wk    = (const float*)d_in[4];
    const float* wlr   = (const float*)d_in[5];
    const float* blr   = (const float*)d_in[6];
    const float* wrl   = (const float*)d_in[7];
    const float* brl   = (const float*)d_in[8];
    const float* alpha = (const float*)d_in[9];
    const float* beta  = (const float*)d_in[10];
    const float* gamma = (const float*)d_in[11];
    // d_in[12] (masking_matrix) intentionally unused: analytic k-intervals +
    // prefix sum replace the O(N^3) einsum.

    unsigned short* h_bf  = (unsigned short*)d_ws;                 // 3072x512
    unsigned short* w_bf  = h_bf + (size_t)M_ROWS * DIM;           // 1024x512
    unsigned short* qk_bf = w_bf + (size_t)QK_COLS * DIM;          // 3072x1024
    float* left  = (float*)(qk_bf + (size_t)M_ROWS * QK_COLS);     // 3072
    float* right = left + M_ROWS;                                  // 3072
    float* raw   = right + M_ROWS;                                 // 8*384*384

    float* out_r  = (float*)d_out;
    float* out_am = out_r + (size_t)BATCH * N_SEQ * N_SEQ;

    prep<<<1024, 256, 0, stream>>>(h, Wq, Wk, wlr, blr, wrl, brl,
                                   h_bf, w_bf, left, right);
    dim3 g1(M_ROWS / 64, QK_COLS / 64);         // 48 x 16
    qk_gemm<<<g1, 256, 0, stream>>>(h_bf, w_bf, bq, qk_bf);
    dim3 g2(N_SEQ / 64, N_SEQ / 64, BATCH);     // 6 x 6 x 8
    score_gemm<<<g2, 256, 0, stream>>>(qk_bf, left, right, alpha, beta, gamma, raw);
    dim3 g3(N_SEQ, BATCH);
    finalize<<<g3, 384, 0, stream>>>(raw, mask, out_r, out_am);
}

// Round 7
// 301.577 us; speedup vs baseline: 1.0641x; 1.0011x over previous
//
#include <hip/hip_runtime.h>
#include <math.h>

#define N_SEQ 384
#define DIM 512
#define BATCH 8
#define M_ROWS (BATCH * N_SEQ)   // 3072
#define QK_COLS (2 * DIM)        // 1024: cols 0..511 = q, 512..1023 = k

typedef short v8s __attribute__((ext_vector_type(8)));   // 8 bf16 (4 VGPRs)
typedef float v4f __attribute__((ext_vector_type(4)));   // MFMA f32 acc

__device__ inline unsigned short f2bf(float f) {
    union { float f; unsigned u; } c; c.f = f;
    unsigned u = c.u;
    u += 0x7fffu + ((u >> 16) & 1u);   // RNE (inputs finite)
    return (unsigned short)(u >> 16);
}

// ---------------------------------------------------------------------------
// Kernel 0: prep = cast h/Wq/Wk -> bf16  +  left/right GEMVs, fused.
// One wave per 512-elem row.  Wave-tasks 0..3071 = h rows (cast + GEMV),
// 3072..4095 = Wq/Wk rows (cast only).  Grid 1024 x 256.
// Cast ONCE here, reuse bf16 in the GEMMs (round-5 cast-in-loop regressed).
// ---------------------------------------------------------------------------
__global__ __launch_bounds__(256) void prep(
    const float* __restrict__ h, const float* __restrict__ Wq,
    const float* __restrict__ Wk, const float* __restrict__ wlr,
    const float* __restrict__ blr, const float* __restrict__ wrl,
    const float* __restrict__ brl, unsigned short* __restrict__ h_bf,
    unsigned short* __restrict__ w_bf, float* __restrict__ left,
    float* __restrict__ right)
{
    const int wv = threadIdx.x >> 6, lane = threadIdx.x & 63;
    const int task = blockIdx.x * 4 + wv;          // 0..4095
    const float* src; unsigned short* dst;
    if (task < M_ROWS) {
        src = h + (size_t)task * DIM;
        dst = h_bf + (size_t)task * DIM;
    } else {
        const int r = task - M_ROWS;               // 0..1023
        src = (r < DIM) ? (Wq + (size_t)r * DIM) : (Wk + (size_t)(r - DIM) * DIM);
        dst = w_bf + (size_t)r * DIM;
    }
    const float4* s4 = (const float4*)src;
    const float4 v0 = s4[lane];        // elems lane*4 .. +3
    const float4 v1 = s4[lane + 64];   // elems 256+lane*4 .. +3
    ushort4 o0, o1;
    o0.x = f2bf(v0.x); o0.y = f2bf(v0.y); o0.z = f2bf(v0.z); o0.w = f2bf(v0.w);
    o1.x = f2bf(v1.x); o1.y = f2bf(v1.y); o1.z = f2bf(v1.z); o1.w = f2bf(v1.w);
    *(ushort4*)(dst + lane * 4)       = o0;
    *(ushort4*)(dst + 256 + lane * 4) = o1;
    if (task < M_ROWS) {
        const float4* wl4 = (const float4*)wlr;
        const float4* wr4 = (const float4*)wrl;
        const float4 a0 = wl4[lane], a1 = wl4[lane + 64];
        const float4 c0 = wr4[lane], c1 = wr4[lane + 64];
        float sl = v0.x * a0.x + v0.y * a0.y + v0.z * a0.z + v0.w * a0.w
                 + v1.x * a1.x + v1.y * a1.y + v1.z * a1.z + v1.w * a1.w;
        float sr = v0.x * c0.x + v0.y * c0.y + v0.z * c0.z + v0.w * c0.w
                 + v1.x * c1.x + v1.y * c1.y + v1.z * c1.z + v1.w * c1.w;
#pragma unroll
        for (int off = 32; off > 0; off >>= 1) {
            sl += __shfl_down(sl, off);
            sr += __shfl_down(sr, off);
        }
        if (lane == 0) {
            left[task]  = sl + blr[0];
            right[task] = sr + brl[0];
        }
    }
}

// ---------------------------------------------------------------------------
// Kernel 1: MFMA qk projection, 64x64 tile, BK=128 (four 32-wide LDS stages
// per barrier-pair -> 16 MFMAs/wave between barriers, 4 K-iters).
// LDS 41 KB -> still 3 blocks/CU (grid-limited), unlike m132's 64 KB cliff.
// Grid 48x16 = 768 blocks.  LDS rows padded to 40 bf16 (2-way = free).
// ---------------------------------------------------------------------------
__global__ __launch_bounds__(256) void qk_gemm(
    const unsigned short* __restrict__ A,   // h_bf 3072x512
    const unsigned short* __restrict__ Bm,  // w_bf 1024x512
    const float* __restrict__ bq,
    unsigned short* __restrict__ C)         // qk_bf 3072x1024
{
    __shared__ unsigned short As[4][64][40];
    __shared__ unsigned short Bs[4][64][40];
    const int bm = blockIdx.x * 64;
    const int bn = blockIdx.y * 64;
    const int t = threadIdx.x;
    const int wv = t >> 6, lane = t & 63;
    const int wm = (wv & 1) * 32, wn = (wv >> 1) * 32;
    const int lm = lane & 15, quad = lane >> 4;
    const int srow = t >> 2, skc = (t & 3) * 8;
    v4f acc[2][2] = {};
    for (int k0 = 0; k0 < DIM; k0 += 128) {
        const unsigned short* ap = A  + (size_t)(bm + srow) * DIM + k0 + skc;
        const unsigned short* bp = Bm + (size_t)(bn + srow) * DIM + k0 + skc;
        v8s a[4], b[4];
#pragma unroll
        for (int q = 0; q < 4; ++q) {
            a[q] = *(const v8s*)(ap + q * 32);
            b[q] = *(const v8s*)(bp + q * 32);
        }
        __syncthreads();
#pragma unroll
        for (int q = 0; q < 4; ++q) {
            *(v8s*)&As[q][srow][skc] = a[q];
            *(v8s*)&Bs[q][srow][skc] = b[q];
        }
        __syncthreads();
#pragma unroll
        for (int half = 0; half < 4; ++half) {
            v8s af[2], bf[2];
#pragma unroll
            for (int i = 0; i < 2; ++i) af[i] = *(const v8s*)&As[half][wm + i * 16 + lm][quad * 8];
#pragma unroll
            for (int j = 0; j < 2; ++j) bf[j] = *(const v8s*)&Bs[half][wn + j * 16 + lm][quad * 8];
#pragma unroll
            for (int i = 0; i < 2; ++i)
#pragma unroll
                for (int j = 0; j < 2; ++j)
                    acc[i][j] = __builtin_amdgcn_mfma_f32_16x16x32_bf16(af[i], bf[j], acc[i][j], 0, 0, 0);
        }
    }
#pragma unroll
    for (int i = 0; i < 2; ++i)
#pragma unroll
        for (int j = 0; j < 2; ++j) {
            const int col = bn + wn + j * 16 + lm;
            const float bias = (col < DIM) ? bq[col] : 0.f;
#pragma unroll
            for (int r = 0; r < 4; ++r) {
                const int row = bm + wm + i * 16 + quad * 4 + r;
                C[(size_t)row * QK_COLS + col] = f2bf(acc[i][j][r] + bias);
            }
        }
}

// ---------------------------------------------------------------------------
// Kernel 2: MFMA batched scores q_b @ k_b^T fused with
// raw = clip(alpha*s + beta*d + gamma).  64x64 tile, BK=128, grid 6x6x8=288.
// ---------------------------------------------------------------------------
__global__ __launch_bounds__(256) void score_gemm(
    const unsigned short* __restrict__ QK, const float* __restrict__ left,
    const float* __restrict__ right, const float* __restrict__ alpha,
    const float* __restrict__ beta, const float* __restrict__ gamma,
    float* __restrict__ raw)
{
    __shared__ unsigned short As[4][64][40];
    __shared__ unsigned short Bs[4][64][40];
    const int b  = blockIdx.z;
    const int bi = blockIdx.x * 64, bj = blockIdx.y * 64;
    const int t = threadIdx.x;
    const int wv = t >> 6, lane = t & 63;
    const int wm = (wv & 1) * 32, wn = (wv >> 1) * 32;
    const int lm = lane & 15, quad = lane >> 4;
    const int srow = t >> 2, skc = (t & 3) * 8;
    const unsigned short* qb = QK + (size_t)(b * N_SEQ) * QK_COLS;
    v4f acc[2][2] = {};
    for (int k0 = 0; k0 < DIM; k0 += 128) {
        const unsigned short* ap = qb + (size_t)(bi + srow) * QK_COLS + k0 + skc;
        const unsigned short* bp = qb + (size_t)(bj + srow) * QK_COLS + DIM + k0 + skc;
        v8s a[4], b4[4];
#pragma unroll
        for (int q = 0; q < 4; ++q) {
            a[q]  = *(const v8s*)(ap + q * 32);
            b4[q] = *(const v8s*)(bp + q * 32);
        }
        __syncthreads();
#pragma unroll
        for (int q = 0; q < 4; ++q) {
            *(v8s*)&As[q][srow][skc] = a[q];
            *(v8s*)&Bs[q][srow][skc] = b4[q];
        }
        __syncthreads();
#pragma unroll
        for (int half = 0; half < 4; ++half) {
            v8s af[2], bf[2];
#pragma unroll
            for (int i = 0; i < 2; ++i) af[i] = *(const v8s*)&As[half][wm + i * 16 + lm][quad * 8];
#pragma unroll
            for (int j = 0; j < 2; ++j) bf[j] = *(const v8s*)&Bs[half][wn + j * 16 + lm][quad * 8];
#pragma unroll
            for (int i = 0; i < 2; ++i)
#pragma unroll
                for (int j = 0; j < 2; ++j)
                    acc[i][j] = __builtin_amdgcn_mfma_f32_16x16x32_bf16(af[i], bf[j], acc[i][j], 0, 0, 0);
        }
    }
    const float al = alpha[0], be = beta[0], ga = gamma[0];
#pragma unroll
    for (int i = 0; i < 2; ++i)
#pragma unroll
        for (int j = 0; j < 2; ++j) {
            const int jcol = bj + wn + j * 16 + lm;
#pragma unroll
            for (int r = 0; r < 4; ++r) {
                const int irow = bi + wm + i * 16 + quad * 4 + r;
                const float lv = left[b * N_SEQ + irow];
                const float rv = right[b * N_SEQ + irow];
                const float dterm = (jcol >= irow) ? lv : rv;
                float v = fmaf(al, acc[i][j][r], fmaf(be, dterm, ga));
                v = fminf(fmaxf(v, -16.f), 14.f);
                raw[((size_t)b * N_SEQ + irow) * N_SEQ + jcol] = v;
            }
        }
}

// ---------------------------------------------------------------------------
// Kernel 3: finalize, one WAVE per (b,i) row.  Block 256 thr = 4 waves,
// grid (96, 8) = 768 blocks.  Segmented c-major scan: lane owns cols
// j = c*64+lane (c=0..5) -> fully coalesced loads/stores; 6 wave-scans give
// the exclusive prefix P; analytic mask intervals as before:
//   i<j: (P[j]-P[i+1]) + (P[i]-P[max(2i-j+1,0)])
//   i>j: (P[i]-P[j+1]) + (P[min(2i-j+1,N)]-P[i+1])
// masking_matrix input never touched.
// ---------------------------------------------------------------------------
__global__ __launch_bounds__(256) void finalize(
    const float* __restrict__ raw, const float* __restrict__ mask,
    float* __restrict__ out_r, float* __restrict__ out_am)
{
    const int n = N_SEQ;
    __shared__ float P[4][N_SEQ + 1];   // per-wave prefix array
    const int wv = threadIdx.x >> 6, lane = threadIdx.x & 63;
    const int b = blockIdx.y;
    const int i = blockIdx.x * 4 + wv;
    const float* rowp = raw + ((size_t)b * n + i) * n;

    float x[6], l1[6];
#pragma unroll
    for (int c = 0; c < 6; ++c) {
        x[c]  = rowp[c * 64 + lane];
        l1[c] = -log1pf(expf(x[c]));     // log(1 - sigmoid(x))
    }
    // segmented scan: per c, wave-inclusive-scan; carry segment totals.
    float base = 0.f;
#pragma unroll
    for (int c = 0; c < 6; ++c) {
        float incl = l1[c];
#pragma unroll
        for (int off = 1; off < 64; off <<= 1) {
            const float tt = __shfl_up(incl, off);
            if (lane >= off) incl += tt;
        }
        P[wv][1 + c * 64 + lane] = base + incl;
        base += __shfl(incl, 63);        // segment total broadcast
    }
    if (lane == 0) P[wv][0] = 0.f;
    __syncthreads();

    const float mi = mask[b * n + i];
#pragma unroll
    for (int c = 0; c < 6; ++c) {
        const int j = c * 64 + lane;
        float s = 0.f;
        if (i < j) {
            int lo2 = 2 * i - j + 1; if (lo2 < 0) lo2 = 0;
            s = (P[wv][j] - P[wv][i + 1]) + (P[wv][i] - P[wv][lo2]);
        } else if (i > j) {
            int hi2 = 2 * i - j + 1; if (hi2 > n) hi2 = n;
            s = (P[wv][i] - P[wv][j + 1]) + (P[wv][hi2] - P[wv][i + 1]);
        }
        float r = s + (x[c] + l1[c]);    // lp = x + l1
        if (i == j) r -= 10000.f;
        const size_t o = ((size_t)b * n + i) * n + j;
        out_r[o]  = r;
        out_am[o] = mi * mask[b * n + j];
    }
}

// ---------------------------------------------------------------------------
extern "C" void kernel_launch(void* const* d_in, const int* in_sizes, int n_in,
                              void* d_out, int out_size, void* d_ws, size_t ws_size,
                              hipStream_t stream) {
    const float* h     = (const float*)d_in[0];
    const float* mask  = (const float*)d_in[1];
    const float* Wq    = (const float*)d_in[2];
    const float* bq    = (const float*)d_in[3];
    const float* Wk    = (const float*)d_in[4];
    const float* wlr   = (const float*)d_in[5];
    const float* blr   = (const float*)d_in[6];
    const float* wrl   = (const float*)d_in[7];
    const float* brl   = (const float*)d_in[8];
    const float* alpha = (const float*)d_in[9];
    const float* beta  = (const float*)d_in[10];
    const float* gamma = (const float*)d_in[11];
    // d_in[12] (masking_matrix) intentionally unused: analytic k-intervals +
    // prefix sum replace the O(N^3) einsum.

    unsigned short* h_bf  = (unsigned short*)d_ws;                 // 3072x512
    unsigned short* w_bf  = h_bf + (size_t)M_ROWS * DIM;           // 1024x512
    unsigned short* qk_bf = w_bf + (size_t)QK_COLS * DIM;          // 3072x1024
    float* left  = (float*)(qk_bf + (size_t)M_ROWS * QK_COLS);     // 3072
    float* right = left + M_ROWS;                                  // 3072
    float* raw   = right + M_ROWS;                                 // 8*384*384

    float* out_r  = (float*)d_out;
    float* out_am = out_r + (size_t)BATCH * N_SEQ * N_SEQ;

    prep<<<1024, 256, 0, stream>>>(h, Wq, Wk, wlr, blr, wrl, brl,
                                   h_bf, w_bf, left, right);
    dim3 g1(M_ROWS / 64, QK_COLS / 64);         // 48 x 16
    qk_gemm<<<g1, 256, 0, stream>>>(h_bf, w_bf, bq, qk_bf);
    dim3 g2(N_SEQ / 64, N_SEQ / 64, BATCH);     // 6 x 6 x 8
    score_gemm<<<g2, 256, 0, stream>>>(qk_bf, left, right, alpha, beta, gamma, raw);
    dim3 g3(M_ROWS / 4 / BATCH, BATCH);         // 96 x 8 (wave per row)
    finalize<<<g3, 256, 0, stream>>>(raw, mask, out_r, out_am);
}